// Round 2
// baseline (346.596 us; speedup 1.0000x reference)
//
#include <hip/hip_runtime.h>

// ---------------------------------------------------------------------------
// CondConv2d  (B=32, C=256, H=W=56, E=4, O=256, K=3, stride=1, pad=1)
//
//   1) transform_pool : x[B,C,H,W] f32 -> xp[B,58,58,C] bf16 (swizzled LDS,
//                       cvt_pk_bf16, uint4 stores) + pool partials + borders
//   2) routing_kernel : reduce pp -> relu(fc1) -> softmax(fc2) -> routing[32][4]
//   3) combine_kernel : grid (256,8); experts in regs; LDS-staged uint4 stores
//   4) conv_gemm      : NEW 8-phase 256x256 implicit GEMM, BK=64, 8 waves,
//                       quadrant-slot LDS (128 KB), counted vmcnt ledger
//                       (8/6/10/-, never 0 in steady state), setprio MFMA.
// ---------------------------------------------------------------------------

#define B_  32
#define C_  256
#define H_  56
#define W_  56
#define HW_ 3136
#define E_  4
#define O_  256
#define HID_ 64
#define HP_ 58
#define PHW_ 3364
#define KK_ 2304

typedef __attribute__((ext_vector_type(8))) short bf16x8;
typedef __attribute__((ext_vector_type(4))) float f32x4;

__device__ __forceinline__ unsigned short f2bf(float f) {
    unsigned int u = __float_as_uint(f);
    u = (u + 0x7FFFu + ((u >> 16) & 1u)) >> 16;   // round-to-nearest-even
    return (unsigned short)u;
}

__device__ __forceinline__ unsigned int cvt_pk_bf16(float lo, float hi) {
    unsigned int r;
    asm("v_cvt_pk_bf16_f32 %0, %1, %2" : "=v"(r) : "v"(lo), "v"(hi));
    return r;
}

__device__ __forceinline__ void load_lds16(const void* g, void* l) {
    // global -> LDS DMA, 16 B per lane; LDS dest = wave-uniform base + lane*16
    __builtin_amdgcn_global_load_lds(
        (__attribute__((address_space(1))) unsigned int*)(unsigned long long)(const char*)g,
        (__attribute__((address_space(3))) unsigned int*)l,
        16, 0, 0);
}

__device__ __forceinline__ void wgbar() {
    asm volatile("" ::: "memory");
    __builtin_amdgcn_s_barrier();
    asm volatile("" ::: "memory");
}

#define VMW(N) asm volatile("s_waitcnt vmcnt(" #N ")" ::: "memory")

// ---------- 1) NCHW f32 -> padded NHWC bf16 + pool partials + borders -------
// grid (56, 2, 32), 256 threads.  (unchanged from round 1)
__global__ __launch_bounds__(256) void transform_pool(const float* __restrict__ x,
                                                      unsigned short* __restrict__ xp,
                                                      float* __restrict__ pp) {
    const int h    = blockIdx.x;       // 0..55
    const int half = blockIdx.y;       // channel half
    const int b    = blockIdx.z;
    const int t    = threadIdx.x;
    const int c0   = half * 128;
    __shared__ alignas(16) float tile[128 * 64];   // 32 KB, swizzled cols
    __shared__ alignas(16) float part[14 * 128];   // 7 KB pool partials

    const float* src = x + ((size_t)(b * C_ + c0) * H_ + h) * W_;
#pragma unroll
    for (int i = t; i < 128 * 14; i += 256) {
        const int c  = i / 14;
        const int w4 = (i % 14) * 4;
        float4 v = *(const float4*)(src + (size_t)c * (H_ * W_) + w4);
        const int wsw = w4 ^ (((c >> 3) & 7) << 2);
        *(float4*)&tile[c * 64 + wsw] = v;         // single b128, aligned
    }

    // border zeroing (fused; xp is poison-initialized every launch)
    unsigned int* ubase = (unsigned int*)(xp + (size_t)b * PHW_ * C_);
    {
        const int hp = h + 1;
        if (t < 128) {                 // cols wp=0,57 for this row, this half
            const int col = (t >> 6) ? 57 : 0;
            const int cu  = t & 63;
            ubase[((size_t)hp * HP_ + col) * 128 + half * 64 + cu] = 0u;
        }
        if (h == 0) {                  // rows hp=0 and hp=57, this half
            for (int i = t; i < HP_ * 64; i += 256) {
                const int pix = i >> 6, cu = i & 63;
                ubase[(size_t)pix * 128 + half * 64 + cu] = 0u;
                ubase[((size_t)57 * HP_ + pix) * 128 + half * 64 + cu] = 0u;
            }
        }
    }
    __syncthreads();

    const int cu  = t & 15;            // 8-channel group (c = 8*cu .. 8*cu+7)
    const int seg = t >> 4;            // w segment: segs 0..13 x 4 cols
    float s0 = 0.f, s1 = 0.f, s2 = 0.f, s3 = 0.f;
    float s4 = 0.f, s5 = 0.f, s6 = 0.f, s7 = 0.f;
    if (seg < 14) {
        const int sw = (cu & 7) << 2;
        unsigned short* ob = xp
            + ((size_t)(b * HP_ + h + 1) * HP_ + (seg * 4 + 1)) * C_ + c0 + cu * 8;
#pragma unroll
        for (int wi = 0; wi < 4; ++wi) {
            const int wc = (seg * 4 + wi) ^ sw;    // swizzled column
            const float* tp = tile + cu * 512 + wc;
            float f0 = tp[0 * 64], f1 = tp[1 * 64], f2 = tp[2 * 64], f3 = tp[3 * 64];
            float f4 = tp[4 * 64], f5 = tp[5 * 64], f6 = tp[6 * 64], f7 = tp[7 * 64];
            s0 += f0; s1 += f1; s2 += f2; s3 += f3;
            s4 += f4; s5 += f5; s6 += f6; s7 += f7;
            uint4 pk;
            pk.x = cvt_pk_bf16(f0, f1);
            pk.y = cvt_pk_bf16(f2, f3);
            pk.z = cvt_pk_bf16(f4, f5);
            pk.w = cvt_pk_bf16(f6, f7);
            *(uint4*)(ob + (size_t)wi * C_) = pk;  // 16 B/lane, coalesced
        }
        *(float4*)&part[seg * 128 + cu * 8 + 0] = make_float4(s0, s1, s2, s3);
        *(float4*)&part[seg * 128 + cu * 8 + 4] = make_float4(s4, s5, s6, s7);
    }
    __syncthreads();
    if (t < 128) {
        float v = 0.f;
#pragma unroll
        for (int sgi = 0; sgi < 14; ++sgi) v += part[sgi * 128 + t];
        pp[((size_t)(b * C_ + c0 + t)) * 56 + h] = v;
    }
}

// ------------------------------ 2) routing ----------------------------------
__global__ void routing_kernel(const float* __restrict__ pp,
                               const float* __restrict__ rw1,
                               const float* __restrict__ rb1,
                               const float* __restrict__ rw2,
                               const float* __restrict__ rb2,
                               float* __restrict__ routing) {
    const int b = blockIdx.x;
    const int t = threadIdx.x;
    __shared__ float pl[C_];
    __shared__ float part[256];
    __shared__ float hb[HID_];
    __shared__ float lg[E_];
    {
        const float* p = pp + (size_t)(b * C_ + t) * 56;
        float s = 0.f;
#pragma unroll
        for (int i = 0; i < 14; ++i) {
            float4 v = *(const float4*)(p + 4 * i);
            s += v.x + v.y + v.z + v.w;
        }
        pl[t] = s * (1.0f / (float)HW_);
    }
    __syncthreads();
    const int j = t >> 2, seg = t & 3;
    {
        const float* w = rw1 + j * C_ + seg * 64;
        const float* p = pl + seg * 64;
        float s = 0.0f;
#pragma unroll 8
        for (int cc = 0; cc < 64; ++cc) s += p[cc] * w[cc];
        part[t] = s;
    }
    __syncthreads();
    if (seg == 0) {
        float s = part[t] + part[t + 1] + part[t + 2] + part[t + 3] + rb1[j];
        hb[j] = fmaxf(s, 0.0f);
    }
    __syncthreads();
    if (t < E_) {
        float s = rb2[t];
        for (int jj = 0; jj < HID_; ++jj) s += hb[jj] * rw2[t * HID_ + jj];
        lg[t] = s;
    }
    __syncthreads();
    if (t == 0) {
        float mx = fmaxf(fmaxf(lg[0], lg[1]), fmaxf(lg[2], lg[3]));
        float e0 = expf(lg[0] - mx), e1 = expf(lg[1] - mx);
        float e2 = expf(lg[2] - mx), e3 = expf(lg[3] - mx);
        float inv = 1.0f / (e0 + e1 + e2 + e3);
        routing[b * E_ + 0] = e0 * inv;
        routing[b * E_ + 1] = e1 * inv;
        routing[b * E_ + 2] = e2 * inv;
        routing[b * E_ + 3] = e3 * inv;
    }
}

// --------------------- 3) combined weights, k = r*256+c ---------------------
__global__ void combine_kernel(const float* __restrict__ experts,
                               const float* __restrict__ routing,
                               unsigned short* __restrict__ wcomb) {
    const int o  = blockIdx.x;
    const int bg = blockIdx.y;
    const int c  = threadIdx.x;
    __shared__ alignas(16) unsigned short sh[KK_];
    __shared__ float rt[16];
    if (c < 16) rt[c] = routing[bg * 16 + c];

    float w[E_][9];
#pragma unroll
    for (int e = 0; e < E_; ++e) {
        const float* ep = experts + ((size_t)(e * O_ + o) * C_ + c) * 9;
        float4 v0 = *(const float4*)(ep + 0);
        float4 v1 = *(const float4*)(ep + 4);
        w[e][0] = v0.x; w[e][1] = v0.y; w[e][2] = v0.z; w[e][3] = v0.w;
        w[e][4] = v1.x; w[e][5] = v1.y; w[e][6] = v1.z; w[e][7] = v1.w;
        w[e][8] = ep[8];
    }
    __syncthreads();
#pragma unroll
    for (int bq = 0; bq < 4; ++bq) {
        const float r0 = rt[bq * 4 + 0], r1 = rt[bq * 4 + 1];
        const float r2 = rt[bq * 4 + 2], r3 = rt[bq * 4 + 3];
#pragma unroll
        for (int k = 0; k < 9; ++k) {
            float a = r0 * w[0][k] + r1 * w[1][k] + r2 * w[2][k] + r3 * w[3][k];
            sh[k * C_ + c] = f2bf(a);
        }
        __syncthreads();
        const int b = bg * 4 + bq;
        uint4* dst = (uint4*)(wcomb + (size_t)(b * O_ + o) * KK_);
        const uint4* s4 = (const uint4*)sh;
        for (int idx = c; idx < KK_ / 8; idx += 256) dst[idx] = s4[idx];
        __syncthreads();
    }
}

// --------------------------- 4) 8-phase implicit-GEMM conv ------------------
// BM=BN=256, BK=64, 512 threads (8 waves, wm=wid>>2, wn=wid&3).
// LDS 128 KB: A[2 buf][2 mh-slot][128 row'][64], B[2 buf][2 nh-slot][128 row'][64]
//   A row' = (wm<<6)|(r&63)  for global o-row r  (slot = (r>>6)&1)
//   B row' = (wn<<5)|(r&31)  for tile-pixel  r  (slot = (r>>5)&1)
// Per-row-of-8-chunks XOR swizzle (chunk j at slot j^(row'&7)) -- 0 conflicts.
// Phase = quadrant (mh,nh) x full BK: 16 MFMA, af cached across nh-phases.
// Counted vmcnt ledger (per wave, 2 loads/stage, issue order fixed):
//   steady: ph1 vmcnt(8), ph2 (6), ph3 (10), ph4 --, ph5 (8), ph6 (6),
//           ph7 (10), ph8 --   [never 0]; peeled last iter tightens to 4/0/0.
__global__ __launch_bounds__(512) void conv_gemm(const unsigned short* __restrict__ xp,
                                                 const unsigned short* __restrict__ wcomb,
                                                 float* __restrict__ out) {
    __shared__ alignas(16) unsigned short Alds[2 * 2 * 128 * 64];  // 64 KB
    __shared__ alignas(16) unsigned short Blds[2 * 2 * 128 * 64];  // 64 KB

    const int tid  = threadIdx.x;
    const int lane = tid & 63;
    const int wid  = tid >> 6;
    const int wm   = wid >> 2;          // 0..1  (m-half of 256)
    const int wn   = wid & 3;           // 0..3  (n-quarter of 256)
    const int fm   = lane & 15;
    const int fq   = lane >> 4;

    const int id  = blockIdx.x;         // 416 blocks = 8 XCD * 52
    const int xcd = id & 7;
    const int qq  = id >> 3;            // 0..51
    const int b   = (qq / 13) * 8 + xcd;
    const int n0  = (qq % 13) * 256;

    // ---- staging constants -------------------------------------------------
    const int rl = wid * 8 + (lane >> 3);                  // 0..63
    const int qg = (lane & 7) ^ ((lane >> 3) & 7);         // swizzled chunk
    const unsigned short* abase = wcomb + ((size_t)b * O_ + rl) * KK_ + qg * 8;
    const unsigned short* bbase = xp + (size_t)b * PHW_ * C_ + qg * 8;
    unsigned int boffs[2][2];
#pragma unroll
    for (int u = 0; u < 2; ++u)
#pragma unroll
        for (int s = 0; s < 2; ++s) {
            int pi = (u * 2 + (rl >> 5)) * 64 + s * 32 + (rl & 31);
            int p  = n0 + pi;
            if (p > HW_ - 1) p = HW_ - 1;
            boffs[u][s] = (unsigned int)((p / W_) * HP_ + (p % W_)) * C_;
        }

#define STAGE_A(BUF, S, KT)                                                     \
    {                                                                           \
        const unsigned short* asrc_ = abase + (size_t)((S) * 64) * KK_ + (KT) * 64; \
        load_lds16(asrc_,                    Alds + (((BUF) * 2 + (S)) * 128 + wid * 8) * 64);      \
        load_lds16(asrc_ + (size_t)128 * KK_, Alds + (((BUF) * 2 + (S)) * 128 + 64 + wid * 8) * 64); \
    }

#define STAGE_B(BUF, S, KT)                                                     \
    {                                                                           \
        const int r9_  = (KT) >> 2;                                             \
        const int duB_ = ((r9_ / 3) * HP_ + (r9_ % 3)) * C_ + ((KT) & 3) * 64;  \
        load_lds16(bbase + boffs[0][S] + duB_, Blds + (((BUF) * 2 + (S)) * 128 + wid * 8) * 64);      \
        load_lds16(bbase + boffs[1][S] + duB_, Blds + (((BUF) * 2 + (S)) * 128 + 64 + wid * 8) * 64); \
    }

    // ---- fragments ---------------------------------------------------------
    f32x4 acc[8][4];
#pragma unroll
    for (int i = 0; i < 8; ++i)
#pragma unroll
        for (int j = 0; j < 4; ++j) acc[i][j] = (f32x4){0.f, 0.f, 0.f, 0.f};
    bf16x8 af[4][2];

    const int colk0 = ((0 + fq) ^ (fm & 7)) * 8;
    const int colk1 = ((4 + fq) ^ (fm & 7)) * 8;
    const int arow  = (wm * 64 + fm) * 64;   // + q*1024 gives row' = (wm<<6)|(q*16+fm)
    const int brow  = (wn * 32 + fm) * 64;   // + j*1024 gives row' = (wn<<5)|(j*16+fm)

#define PHASE(MH, NH, BUF, WCODE, STAGE_STMT, RDAF)                             \
    {                                                                           \
        WCODE;                                                                  \
        wgbar();                                                                \
        if (RDAF) {                                                             \
            _Pragma("unroll")                                                   \
            for (int q_ = 0; q_ < 4; ++q_) {                                    \
                af[q_][0] = *(const bf16x8*)(Alds + (((BUF) * 2 + (MH)) * 128) * 64 + arow + q_ * 1024 + colk0); \
                af[q_][1] = *(const bf16x8*)(Alds + (((BUF) * 2 + (MH)) * 128) * 64 + arow + q_ * 1024 + colk1); \
            }                                                                   \
        }                                                                       \
        bf16x8 bv[2][2];                                                        \
        _Pragma("unroll")                                                       \
        for (int j_ = 0; j_ < 2; ++j_) {                                        \
            bv[j_][0] = *(const bf16x8*)(Blds + (((BUF) * 2 + (NH)) * 128) * 64 + brow + j_ * 1024 + colk0); \
            bv[j_][1] = *(const bf16x8*)(Blds + (((BUF) * 2 + (NH)) * 128) * 64 + brow + j_ * 1024 + colk1); \
        }                                                                       \
        STAGE_STMT;                                                             \
        asm volatile("" ::: "memory");                                          \
        __builtin_amdgcn_s_setprio(1);                                          \
        _Pragma("unroll")                                                       \
        for (int q_ = 0; q_ < 4; ++q_)                                          \
            _Pragma("unroll")                                                   \
            for (int j_ = 0; j_ < 2; ++j_) {                                    \
                acc[(MH) * 4 + q_][(NH) * 2 + j_] = __builtin_amdgcn_mfma_f32_16x16x32_bf16( \
                    af[q_][0], bv[j_][0], acc[(MH) * 4 + q_][(NH) * 2 + j_], 0, 0, 0);       \
                acc[(MH) * 4 + q_][(NH) * 2 + j_] = __builtin_amdgcn_mfma_f32_16x16x32_bf16( \
                    af[q_][1], bv[j_][1], acc[(MH) * 4 + q_][(NH) * 2 + j_], 0, 0, 0);       \
            }                                                                   \
        __builtin_amdgcn_s_setprio(0);                                          \
    }

    // ---- prologue: kt0 fully + kt1 A0,B0 (ledger order!) -------------------
    STAGE_A(0, 0, 0); STAGE_B(0, 0, 0); STAGE_A(0, 1, 0); STAGE_B(0, 1, 0);
    STAGE_A(1, 0, 1); STAGE_B(1, 0, 1);

    // ---- main loop: iters 0..16, K-tiles kt0=2i (buf0), kt1=2i+1 (buf1) ----
#pragma unroll 1
    for (int i = 0; i < 17; ++i) {
        const int k2 = 2 * i;
        PHASE(0, 0, 0, VMW(8),  STAGE_A(1, 1, k2 + 1), 1)
        PHASE(0, 1, 0, VMW(6),  STAGE_B(1, 1, k2 + 1), 0)
        PHASE(1, 0, 0, VMW(10), STAGE_A(0, 0, k2 + 2), 1)
        PHASE(1, 1, 0,        , STAGE_B(0, 0, k2 + 2), 0)
        PHASE(0, 0, 1, VMW(8),  STAGE_A(0, 1, k2 + 2), 1)
        PHASE(0, 1, 1, VMW(6),  STAGE_B(0, 1, k2 + 2), 0)
        PHASE(1, 0, 1, VMW(10), STAGE_A(1, 0, k2 + 3), 1)
        PHASE(1, 1, 1,        , STAGE_B(1, 0, k2 + 3), 0)
    }
    // ---- peeled final iter: kt0=34, kt1=35; no dead prefetch, tight waits --
    PHASE(0, 0, 0, VMW(8),  STAGE_A(1, 1, 35), 1)
    PHASE(0, 1, 0, VMW(6),  STAGE_B(1, 1, 35), 0)
    PHASE(1, 0, 0, VMW(10), (void)0, 1)
    PHASE(1, 1, 0,        , (void)0, 0)
    PHASE(0, 0, 1, VMW(4),  (void)0, 1)
    PHASE(0, 1, 1, VMW(0),  (void)0, 0)
    PHASE(1, 0, 1, VMW(0),  (void)0, 1)
    PHASE(1, 1, 1,        , (void)0, 0)

    // ---- epilogue: D layout col(n)=lane&15, row(m)=(lane>>4)*4+reg ---------
#pragma unroll
    for (int mi = 0; mi < 8; ++mi) {
        const int o = wm * 128 + mi * 16 + fq * 4;
#pragma unroll
        for (int ni = 0; ni < 4; ++ni) {
            const int p = n0 + wn * 64 + ni * 16 + fm;
            if (p < HW_) {
                float* po = out + ((size_t)(b * O_ + o)) * HW_ + p;
                po[0 * HW_] = acc[mi][ni][0];
                po[1 * HW_] = acc[mi][ni][1];
                po[2 * (size_t)HW_] = acc[mi][ni][2];
                po[3 * (size_t)HW_] = acc[mi][ni][3];
            }
        }
    }
#undef PHASE
#undef STAGE_A
#undef STAGE_B
}

// ---------------------------------------------------------------------------
extern "C" void kernel_launch(void* const* d_in, const int* in_sizes, int n_in,
                              void* d_out, int out_size, void* d_ws, size_t ws_size,
                              hipStream_t stream) {
    const float* x       = (const float*)d_in[0];
    const float* experts = (const float*)d_in[1];
    const float* rw1     = (const float*)d_in[2];
    const float* rb1     = (const float*)d_in[3];
    const float* rw2     = (const float*)d_in[4];
    const float* rb2     = (const float*)d_in[5];
    float* out = (float*)d_out;

    const size_t XP_OFF = 0;                                   // 55,115,776 B
    const size_t WC_OFF = 55115776;                            // 37,748,736 B
    const size_t PP_OFF = WC_OFF + 37748736;                   // 1,835,008 B
    const size_t RT_OFF = PP_OFF + 1835008;                    // 512 B
    unsigned short* xp    = (unsigned short*)((char*)d_ws + XP_OFF);
    unsigned short* wcomb = (unsigned short*)((char*)d_ws + WC_OFF);
    float* pp      = (float*)((char*)d_ws + PP_OFF);
    float* routing = (float*)((char*)d_ws + RT_OFF);

    transform_pool<<<dim3(H_, 2, B_), dim3(256), 0, stream>>>(x, xp, pp);
    routing_kernel<<<dim3(B_), dim3(256), 0, stream>>>(pp, rw1, rb1, rw2, rb2, routing);
    combine_kernel<<<dim3(O_, 8), dim3(256), 0, stream>>>(experts, routing, wcomb);
    conv_gemm<<<dim3(416), dim3(512), 0, stream>>>(xp, wcomb, out);
}

// Round 3
// 337.257 us; speedup vs baseline: 1.0277x; 1.0277x over previous
//
#include <hip/hip_runtime.h>

// ---------------------------------------------------------------------------
// CondConv2d  (B=32, C=256, H=W=56, E=4, O=256, K=3, stride=1, pad=1)
//
//   1) transform_pool : x[B,C,H,W] f32 -> xp[B,58,58,C] bf16 (swizzled LDS,
//                       cvt_pk_bf16, uint4 stores) + pool partials + borders
//   2) routing_kernel : reduce pp -> relu(fc1) -> softmax(fc2) -> routing[32][4]
//   3) combine_kernel : grid (256,8); experts in regs; LDS-staged uint4 stores
//   4) conv_gemm      : 8-phase 256x256 implicit GEMM, BK=64, 8 waves,
//                       m201-template phases: reads-before-barrier, dual
//                       barrier, lgkmcnt(0)+sched_barrier, setprio MFMA,
//                       ONE vmcnt(6) per K-tile (counted, never 0 in loop).
// ---------------------------------------------------------------------------

#define B_  32
#define C_  256
#define H_  56
#define W_  56
#define HW_ 3136
#define E_  4
#define O_  256
#define HID_ 64
#define HP_ 58
#define PHW_ 3364
#define KK_ 2304

typedef __attribute__((ext_vector_type(8))) short bf16x8;
typedef __attribute__((ext_vector_type(4))) float f32x4;

__device__ __forceinline__ unsigned short f2bf(float f) {
    unsigned int u = __float_as_uint(f);
    u = (u + 0x7FFFu + ((u >> 16) & 1u)) >> 16;   // round-to-nearest-even
    return (unsigned short)u;
}

__device__ __forceinline__ unsigned int cvt_pk_bf16(float lo, float hi) {
    unsigned int r;
    asm("v_cvt_pk_bf16_f32 %0, %1, %2" : "=v"(r) : "v"(lo), "v"(hi));
    return r;
}

__device__ __forceinline__ void load_lds16(const void* g, void* l) {
    // global -> LDS DMA, 16 B per lane; LDS dest = wave-uniform base + lane*16
    __builtin_amdgcn_global_load_lds(
        (__attribute__((address_space(1))) unsigned int*)(unsigned long long)(const char*)g,
        (__attribute__((address_space(3))) unsigned int*)l,
        16, 0, 0);
}

__device__ __forceinline__ void wgbar() {
    asm volatile("" ::: "memory");
    __builtin_amdgcn_s_barrier();
    asm volatile("" ::: "memory");
}

#define VMW(N) asm volatile("s_waitcnt vmcnt(" #N ")" ::: "memory")
#define LGKM(N) asm volatile("s_waitcnt lgkmcnt(" #N ")" ::: "memory")

// ---------- 1) NCHW f32 -> padded NHWC bf16 + pool partials + borders -------
// grid (56, 2, 32), 256 threads.  (unchanged)
__global__ __launch_bounds__(256) void transform_pool(const float* __restrict__ x,
                                                      unsigned short* __restrict__ xp,
                                                      float* __restrict__ pp) {
    const int h    = blockIdx.x;       // 0..55
    const int half = blockIdx.y;       // channel half
    const int b    = blockIdx.z;
    const int t    = threadIdx.x;
    const int c0   = half * 128;
    __shared__ alignas(16) float tile[128 * 64];   // 32 KB, swizzled cols
    __shared__ alignas(16) float part[14 * 128];   // 7 KB pool partials

    const float* src = x + ((size_t)(b * C_ + c0) * H_ + h) * W_;
#pragma unroll
    for (int i = t; i < 128 * 14; i += 256) {
        const int c  = i / 14;
        const int w4 = (i % 14) * 4;
        float4 v = *(const float4*)(src + (size_t)c * (H_ * W_) + w4);
        const int wsw = w4 ^ (((c >> 3) & 7) << 2);
        *(float4*)&tile[c * 64 + wsw] = v;         // single b128, aligned
    }

    // border zeroing (fused; xp is poison-initialized every launch)
    unsigned int* ubase = (unsigned int*)(xp + (size_t)b * PHW_ * C_);
    {
        const int hp = h + 1;
        if (t < 128) {                 // cols wp=0,57 for this row, this half
            const int col = (t >> 6) ? 57 : 0;
            const int cu  = t & 63;
            ubase[((size_t)hp * HP_ + col) * 128 + half * 64 + cu] = 0u;
        }
        if (h == 0) {                  // rows hp=0 and hp=57, this half
            for (int i = t; i < HP_ * 64; i += 256) {
                const int pix = i >> 6, cu = i & 63;
                ubase[(size_t)pix * 128 + half * 64 + cu] = 0u;
                ubase[((size_t)57 * HP_ + pix) * 128 + half * 64 + cu] = 0u;
            }
        }
    }
    __syncthreads();

    const int cu  = t & 15;            // 8-channel group (c = 8*cu .. 8*cu+7)
    const int seg = t >> 4;            // w segment: segs 0..13 x 4 cols
    float s0 = 0.f, s1 = 0.f, s2 = 0.f, s3 = 0.f;
    float s4 = 0.f, s5 = 0.f, s6 = 0.f, s7 = 0.f;
    if (seg < 14) {
        const int sw = (cu & 7) << 2;
        unsigned short* ob = xp
            + ((size_t)(b * HP_ + h + 1) * HP_ + (seg * 4 + 1)) * C_ + c0 + cu * 8;
#pragma unroll
        for (int wi = 0; wi < 4; ++wi) {
            const int wc = (seg * 4 + wi) ^ sw;    // swizzled column
            const float* tp = tile + cu * 512 + wc;
            float f0 = tp[0 * 64], f1 = tp[1 * 64], f2 = tp[2 * 64], f3 = tp[3 * 64];
            float f4 = tp[4 * 64], f5 = tp[5 * 64], f6 = tp[6 * 64], f7 = tp[7 * 64];
            s0 += f0; s1 += f1; s2 += f2; s3 += f3;
            s4 += f4; s5 += f5; s6 += f6; s7 += f7;
            uint4 pk;
            pk.x = cvt_pk_bf16(f0, f1);
            pk.y = cvt_pk_bf16(f2, f3);
            pk.z = cvt_pk_bf16(f4, f5);
            pk.w = cvt_pk_bf16(f6, f7);
            *(uint4*)(ob + (size_t)wi * C_) = pk;  // 16 B/lane, coalesced
        }
        *(float4*)&part[seg * 128 + cu * 8 + 0] = make_float4(s0, s1, s2, s3);
        *(float4*)&part[seg * 128 + cu * 8 + 4] = make_float4(s4, s5, s6, s7);
    }
    __syncthreads();
    if (t < 128) {
        float v = 0.f;
#pragma unroll
        for (int sgi = 0; sgi < 14; ++sgi) v += part[sgi * 128 + t];
        pp[((size_t)(b * C_ + c0 + t)) * 56 + h] = v;
    }
}

// ------------------------------ 2) routing ----------------------------------
__global__ void routing_kernel(const float* __restrict__ pp,
                               const float* __restrict__ rw1,
                               const float* __restrict__ rb1,
                               const float* __restrict__ rw2,
                               const float* __restrict__ rb2,
                               float* __restrict__ routing) {
    const int b = blockIdx.x;
    const int t = threadIdx.x;
    __shared__ float pl[C_];
    __shared__ float part[256];
    __shared__ float hb[HID_];
    __shared__ float lg[E_];
    {
        const float* p = pp + (size_t)(b * C_ + t) * 56;
        float s = 0.f;
#pragma unroll
        for (int i = 0; i < 14; ++i) {
            float4 v = *(const float4*)(p + 4 * i);
            s += v.x + v.y + v.z + v.w;
        }
        pl[t] = s * (1.0f / (float)HW_);
    }
    __syncthreads();
    const int j = t >> 2, seg = t & 3;
    {
        const float* w = rw1 + j * C_ + seg * 64;
        const float* p = pl + seg * 64;
        float s = 0.0f;
#pragma unroll 8
        for (int cc = 0; cc < 64; ++cc) s += p[cc] * w[cc];
        part[t] = s;
    }
    __syncthreads();
    if (seg == 0) {
        float s = part[t] + part[t + 1] + part[t + 2] + part[t + 3] + rb1[j];
        hb[j] = fmaxf(s, 0.0f);
    }
    __syncthreads();
    if (t < E_) {
        float s = rb2[t];
        for (int jj = 0; jj < HID_; ++jj) s += hb[jj] * rw2[t * HID_ + jj];
        lg[t] = s;
    }
    __syncthreads();
    if (t == 0) {
        float mx = fmaxf(fmaxf(lg[0], lg[1]), fmaxf(lg[2], lg[3]));
        float e0 = expf(lg[0] - mx), e1 = expf(lg[1] - mx);
        float e2 = expf(lg[2] - mx), e3 = expf(lg[3] - mx);
        float inv = 1.0f / (e0 + e1 + e2 + e3);
        routing[b * E_ + 0] = e0 * inv;
        routing[b * E_ + 1] = e1 * inv;
        routing[b * E_ + 2] = e2 * inv;
        routing[b * E_ + 3] = e3 * inv;
    }
}

// --------------------- 3) combined weights, k = r*256+c ---------------------
__global__ void combine_kernel(const float* __restrict__ experts,
                               const float* __restrict__ routing,
                               unsigned short* __restrict__ wcomb) {
    const int o  = blockIdx.x;
    const int bg = blockIdx.y;
    const int c  = threadIdx.x;
    __shared__ alignas(16) unsigned short sh[KK_];
    __shared__ float rt[16];
    if (c < 16) rt[c] = routing[bg * 16 + c];

    float w[E_][9];
#pragma unroll
    for (int e = 0; e < E_; ++e) {
        const float* ep = experts + ((size_t)(e * O_ + o) * C_ + c) * 9;
        float4 v0 = *(const float4*)(ep + 0);
        float4 v1 = *(const float4*)(ep + 4);
        w[e][0] = v0.x; w[e][1] = v0.y; w[e][2] = v0.z; w[e][3] = v0.w;
        w[e][4] = v1.x; w[e][5] = v1.y; w[e][6] = v1.z; w[e][7] = v1.w;
        w[e][8] = ep[8];
    }
    __syncthreads();
#pragma unroll
    for (int bq = 0; bq < 4; ++bq) {
        const float r0 = rt[bq * 4 + 0], r1 = rt[bq * 4 + 1];
        const float r2 = rt[bq * 4 + 2], r3 = rt[bq * 4 + 3];
#pragma unroll
        for (int k = 0; k < 9; ++k) {
            float a = r0 * w[0][k] + r1 * w[1][k] + r2 * w[2][k] + r3 * w[3][k];
            sh[k * C_ + c] = f2bf(a);
        }
        __syncthreads();
        const int b = bg * 4 + bq;
        uint4* dst = (uint4*)(wcomb + (size_t)(b * O_ + o) * KK_);
        const uint4* s4 = (const uint4*)sh;
        for (int idx = c; idx < KK_ / 8; idx += 256) dst[idx] = s4[idx];
        __syncthreads();
    }
}

// --------------------------- 4) 8-phase implicit-GEMM conv ------------------
// BM=BN=256, BK=64, 512 threads (8 waves, wm=wid>>2, wn=wid&3).
// LDS 128 KB: A[2buf][2slot][128][64], B[2buf][2slot][128][64] (as round 2;
//   A slot S holds o-rows S*64+{0..63,128..191}; B slot S holds n-half S).
// m201-template phases per K-tile t (buf X = t&1):
//   p1: rd af0(8)+bv0(4); stage B1->t+1; lgkm(8); bar; lgkm(0); MFMA(0,0); bar
//   p2: rd bv1(4);        stage A0->t+2;          bar; lgkm(0); MFMA(0,1); bar
//   p3: rd af1(8);        stage B0->t+2;          bar; lgkm(0); MFMA(1,0); bar
//   p4:                   stage A1->t+2; VMW(6);  bar;          MFMA(1,1); bar
// Ledger: at p4's vmcnt(6), loads <= t.p1 retired -> tile t+1 fully staged.
// WAR: every slot's last ds_read-issue is >=1 phase before its re-stage.
__global__ __launch_bounds__(512) void conv_gemm(const unsigned short* __restrict__ xp,
                                                 const unsigned short* __restrict__ wcomb,
                                                 float* __restrict__ out) {
    __shared__ alignas(16) unsigned short Alds[2 * 2 * 128 * 64];  // 64 KB
    __shared__ alignas(16) unsigned short Blds[2 * 2 * 128 * 64];  // 64 KB

    const int tid  = threadIdx.x;
    const int lane = tid & 63;
    const int wid  = tid >> 6;
    const int wm   = wid >> 2;          // 0..1  (m-half of 256)
    const int wn   = wid & 3;           // 0..3  (n-quarter of 256)
    const int fm   = lane & 15;
    const int fq   = lane >> 4;

    const int id  = blockIdx.x;         // 416 blocks = 8 XCD * 52
    const int xcd = id & 7;
    const int qq  = id >> 3;            // 0..51
    const int b   = (qq / 13) * 8 + xcd;
    const int n0  = (qq % 13) * 256;

    // ---- staging constants -------------------------------------------------
    const int rl = wid * 8 + (lane >> 3);                  // 0..63
    const int qg = (lane & 7) ^ ((lane >> 3) & 7);         // swizzled chunk
    const unsigned short* abase = wcomb + ((size_t)b * O_ + rl) * KK_ + qg * 8;
    const unsigned short* bbase = xp + (size_t)b * PHW_ * C_ + qg * 8;
    unsigned int boffs[2][2];
#pragma unroll
    for (int u = 0; u < 2; ++u)
#pragma unroll
        for (int s = 0; s < 2; ++s) {
            int pi = (u * 2 + (rl >> 5)) * 64 + s * 32 + (rl & 31);
            int p  = n0 + pi;
            if (p > HW_ - 1) p = HW_ - 1;
            boffs[u][s] = (unsigned int)((p / W_) * HP_ + (p % W_)) * C_;
        }

#define STAGE_A(BUF, S, KT)                                                     \
    {                                                                           \
        const unsigned short* asrc_ = abase + (size_t)((S) * 64) * KK_ + (KT) * 64; \
        load_lds16(asrc_,                     Alds + (((BUF) * 2 + (S)) * 128 + wid * 8) * 64);      \
        load_lds16(asrc_ + (size_t)128 * KK_, Alds + (((BUF) * 2 + (S)) * 128 + 64 + wid * 8) * 64); \
    }

#define STAGE_B(BUF, S, KT)                                                     \
    {                                                                           \
        const int r9_  = (KT) >> 2;                                             \
        const int duB_ = ((r9_ / 3) * HP_ + (r9_ % 3)) * C_ + ((KT) & 3) * 64;  \
        load_lds16(bbase + boffs[0][S] + duB_, Blds + (((BUF) * 2 + (S)) * 128 + wid * 8) * 64);      \
        load_lds16(bbase + boffs[1][S] + duB_, Blds + (((BUF) * 2 + (S)) * 128 + 64 + wid * 8) * 64); \
    }

    // ---- fragments ---------------------------------------------------------
    f32x4 acc[8][4];
#pragma unroll
    for (int i = 0; i < 8; ++i)
#pragma unroll
        for (int j = 0; j < 4; ++j) acc[i][j] = (f32x4){0.f, 0.f, 0.f, 0.f};

    const int colk0 = ((0 + fq) ^ (fm & 7)) * 8;
    const int colk1 = ((4 + fq) ^ (fm & 7)) * 8;
    const int arow  = (wm * 64 + fm) * 64;
    const int brow  = (wn * 32 + fm) * 64;

    bf16x8 afA[4][2], afB[4][2], bv0[2][2], bv1[2][2];

#define RD_AF(DST, BUF, MH)                                                     \
    _Pragma("unroll")                                                           \
    for (int q_ = 0; q_ < 4; ++q_) {                                            \
        const unsigned short* ap_ = Alds + (((BUF) * 2 + (MH)) * 128) * 64 + arow + q_ * 1024; \
        DST[q_][0] = *(const bf16x8*)(ap_ + colk0);                             \
        DST[q_][1] = *(const bf16x8*)(ap_ + colk1);                             \
    }

#define RD_BV(DST, BUF, NH)                                                     \
    _Pragma("unroll")                                                           \
    for (int j_ = 0; j_ < 2; ++j_) {                                            \
        const unsigned short* bp_ = Blds + (((BUF) * 2 + (NH)) * 128) * 64 + brow + j_ * 1024; \
        DST[j_][0] = *(const bf16x8*)(bp_ + colk0);                             \
        DST[j_][1] = *(const bf16x8*)(bp_ + colk1);                             \
    }

#define MFMA_Q(MH, NH, AF, BV)                                                  \
    __builtin_amdgcn_s_setprio(1);                                              \
    _Pragma("unroll")                                                           \
    for (int q_ = 0; q_ < 4; ++q_)                                              \
        _Pragma("unroll")                                                       \
        for (int j_ = 0; j_ < 2; ++j_) {                                        \
            acc[(MH) * 4 + q_][(NH) * 2 + j_] = __builtin_amdgcn_mfma_f32_16x16x32_bf16( \
                AF[q_][0], BV[j_][0], acc[(MH) * 4 + q_][(NH) * 2 + j_], 0, 0, 0);       \
            acc[(MH) * 4 + q_][(NH) * 2 + j_] = __builtin_amdgcn_mfma_f32_16x16x32_bf16( \
                AF[q_][1], BV[j_][1], acc[(MH) * 4 + q_][(NH) * 2 + j_], 0, 0, 0);       \
        }                                                                       \
    __builtin_amdgcn_s_setprio(0);

#define DO_TILE(BUF, S1, S2, S3, S4, W4)                                        \
    {                                                                           \
        /* p1: quad(0,0) */                                                     \
        RD_AF(afA, BUF, 0)                                                      \
        RD_BV(bv0, BUF, 0)                                                      \
        S1;                                                                     \
        LGKM(8);                                                                \
        wgbar();                                                                \
        LGKM(0);                                                                \
        __builtin_amdgcn_sched_barrier(0);                                      \
        MFMA_Q(0, 0, afA, bv0)                                                  \
        wgbar();                                                                \
        /* p2: quad(0,1) */                                                     \
        RD_BV(bv1, BUF, 1)                                                      \
        S2;                                                                     \
        wgbar();                                                                \
        LGKM(0);                                                                \
        __builtin_amdgcn_sched_barrier(0);                                      \
        MFMA_Q(0, 1, afA, bv1)                                                  \
        wgbar();                                                                \
        /* p3: quad(1,0) */                                                     \
        RD_AF(afB, BUF, 1)                                                      \
        S3;                                                                     \
        wgbar();                                                                \
        LGKM(0);                                                                \
        __builtin_amdgcn_sched_barrier(0);                                      \
        MFMA_Q(1, 0, afB, bv0)                                                  \
        wgbar();                                                                \
        /* p4: quad(1,1) */                                                     \
        S4;                                                                     \
        W4;                                                                     \
        wgbar();                                                                \
        __builtin_amdgcn_sched_barrier(0);                                      \
        MFMA_Q(1, 1, afB, bv1)                                                  \
        wgbar();                                                                \
    }

    // ---- prologue: tile0 all 4 halves + tile1 {A0,B0,A1}; B1_1 in-loop -----
    STAGE_A(0, 0, 0); STAGE_B(0, 0, 0); STAGE_A(0, 1, 0); STAGE_B(0, 1, 0);
    STAGE_A(1, 0, 1); STAGE_B(1, 0, 1); STAGE_A(1, 1, 1);
    VMW(6);
    wgbar();

    // ---- main loop: tiles 0..33 as 17 x (even buf0, odd buf1) --------------
#pragma unroll 1
    for (int i = 0; i < 17; ++i) {
        const int k2 = 2 * i;
        DO_TILE(0,
                STAGE_B(1, 1, k2 + 1),   // p1: B1 -> tile t+1 (buf1)
                STAGE_A(0, 0, k2 + 2),   // p2: A0 -> tile t+2 (buf0)
                STAGE_B(0, 0, k2 + 2),   // p3: B0 -> tile t+2
                STAGE_A(0, 1, k2 + 2),   // p4: A1 -> tile t+2
                VMW(6))
        DO_TILE(1,
                STAGE_B(0, 1, k2 + 2),   // p1: B1 -> tile t+2 (buf0)
                STAGE_A(1, 0, k2 + 3),   // p2: A0 -> tile t+3 (buf1)
                STAGE_B(1, 0, k2 + 3),   // p3: B0 -> tile t+3
                STAGE_A(1, 1, k2 + 3),   // p4: A1 -> tile t+3
                VMW(6))
    }
    // ---- peeled tiles 34, 35 (no dead prefetch; single tail drain) ---------
    DO_TILE(0, STAGE_B(1, 1, 35), (void)0, (void)0, (void)0, VMW(0))
    DO_TILE(1, (void)0, (void)0, (void)0, (void)0, (void)0)

    // ---- epilogue: D layout col(n)=lane&15, row(m)=(lane>>4)*4+reg ---------
#pragma unroll
    for (int mi = 0; mi < 8; ++mi) {
        const int o = wm * 128 + mi * 16 + fq * 4;
#pragma unroll
        for (int ni = 0; ni < 4; ++ni) {
            const int p = n0 + wn * 64 + ni * 16 + fm;
            if (p < HW_) {
                float* po = out + ((size_t)(b * O_ + o)) * HW_ + p;
                po[0 * HW_] = acc[mi][ni][0];
                po[1 * HW_] = acc[mi][ni][1];
                po[2 * (size_t)HW_] = acc[mi][ni][2];
                po[3 * (size_t)HW_] = acc[mi][ni][3];
            }
        }
    }
#undef DO_TILE
#undef MFMA_Q
#undef RD_AF
#undef RD_BV
#undef STAGE_A
#undef STAGE_B
}

// ---------------------------------------------------------------------------
extern "C" void kernel_launch(void* const* d_in, const int* in_sizes, int n_in,
                              void* d_out, int out_size, void* d_ws, size_t ws_size,
                              hipStream_t stream) {
    const float* x       = (const float*)d_in[0];
    const float* experts = (const float*)d_in[1];
    const float* rw1     = (const float*)d_in[2];
    const float* rb1     = (const float*)d_in[3];
    const float* rw2     = (const float*)d_in[4];
    const float* rb2     = (const float*)d_in[5];
    float* out = (float*)d_out;

    const size_t XP_OFF = 0;                                   // 55,115,776 B
    const size_t WC_OFF = 55115776;                            // 37,748,736 B
    const size_t PP_OFF = WC_OFF + 37748736;                   // 1,835,008 B
    const size_t RT_OFF = PP_OFF + 1835008;                    // 512 B
    unsigned short* xp    = (unsigned short*)((char*)d_ws + XP_OFF);
    unsigned short* wcomb = (unsigned short*)((char*)d_ws + WC_OFF);
    float* pp      = (float*)((char*)d_ws + PP_OFF);
    float* routing = (float*)((char*)d_ws + RT_OFF);

    transform_pool<<<dim3(H_, 2, B_), dim3(256), 0, stream>>>(x, xp, pp);
    routing_kernel<<<dim3(B_), dim3(256), 0, stream>>>(pp, rw1, rb1, rw2, rb2, routing);
    combine_kernel<<<dim3(O_, 8), dim3(256), 0, stream>>>(experts, routing, wcomb);
    conv_gemm<<<dim3(416), dim3(512), 0, stream>>>(xp, wcomb, out);
}